// Round 6
// baseline (611.453 us; speedup 1.0000x reference)
//
#include <hip/hip_runtime.h>
#include <math.h>

#define NPTS   500000
#define GRIDW  64
#define NVOX   (GRIDW*GRIDW*GRIDW)   // 262144
#define C_VOXC 96
#define C_PTC  32
#define OFFD   64
#define HID    96                    // DEC_DIM/2
#define HHALF  48

// bf16 helpers (RNE pack, exact widen) -------------------------------------
__device__ __forceinline__ unsigned f2bf(float f) {
    unsigned u = __float_as_uint(f);
    unsigned r = u + 0x7fffu + ((u >> 16) & 1u);   // round-to-nearest-even
    return r >> 16;
}
__device__ __forceinline__ float bflo(unsigned u) {   // low 16 bits -> f32
    return __uint_as_float(u << 16);
}
__device__ __forceinline__ float bfhi(unsigned u) {   // high 16 bits -> f32
    return __uint_as_float(u & 0xffff0000u);
}

// Branch-free exact-GELU via A&S 7.1.26 erf (abs err 1.5e-7) ---------------
__device__ __forceinline__ float gelu_fast(float s) {
    const float u  = s * 0.70710678118654752440f;
    const float au = fabsf(u);
    const float t  = __fdividef(1.0f, fmaf(0.3275911f, au, 1.0f));
    float p = fmaf(1.061405429f, t, -1.453152027f);
    p = fmaf(p, t, 1.421413741f);
    p = fmaf(p, t, -0.284496736f);
    p = fmaf(p, t, 0.254829592f);
    p *= t;
    const float e = __expf(-u * u);
    float r = fmaf(-p, e, 1.0f);
    r = copysignf(r, u);
    return 0.5f * s * (1.0f + r);
}

// ---------------------------------------------------------------------------
// Kernel A: fold W_off/b_off/b1 through W1's offset rows.
// ---------------------------------------------------------------------------
__global__ void fold_kernel(const float* __restrict__ W_off,
                            const float* __restrict__ b_off,
                            const float* __restrict__ W1,
                            const float* __restrict__ b1,
                            float* __restrict__ Wc,
                            float* __restrict__ bcomb) {
    int j = threadIdx.x;
    if (j >= HID) return;
    float bc = b1[j];
    float w0 = 0.f, w1 = 0.f, w2 = 0.f;
    for (int d = 0; d < OFFD; ++d) {
        float w = W1[(C_PTC + C_VOXC + d) * HID + j];
        bc += b_off[d] * w;
        w0 = fmaf(W_off[0 * OFFD + d], w, w0);
        w1 = fmaf(W_off[1 * OFFD + d], w, w1);
        w2 = fmaf(W_off[2 * OFFD + d], w, w2);
    }
    Wc[0 * HID + j] = w0;
    Wc[1 * HID + j] = w1;
    Wc[2 * HID + j] = w2;
    bcomb[j] = bc;
}

// ---------------------------------------------------------------------------
// Kernel B v3: per-voxel pre-multiply, bf16 output. CLEAN rewrite.
//   vc[v][j] = bf16( sum_c vf[c][v] * W1[32+c][j] )
// launch_bounds(256,2): VGPR cap 256 -> acc[96]+streams (~130) fits, NO SPILL
// (r4 regression root cause: allocator chose 64 VGPR + scratch spill).
// 8 vf loads issued up-front per c-group = 8 independent HBM streams.
// ---------------------------------------------------------------------------
__global__ __launch_bounds__(256, 2) void voxgemm_kernel(
        const float* __restrict__ vf,
        const float* __restrict__ W1,
        uint4* __restrict__ vc) {
    const int v = blockIdx.x * 256 + threadIdx.x;
    const float* __restrict__ W1v = W1 + C_PTC * HID;   // rows 32..127

    float acc[HID];
#pragma unroll
    for (int j = 0; j < HID; ++j) acc[j] = 0.f;

#pragma unroll 1
    for (int c = 0; c < C_VOXC; c += 8) {
        float a[8];
#pragma unroll
        for (int t = 0; t < 8; ++t)
            a[t] = vf[(size_t)(c + t) * NVOX + v];
#pragma unroll
        for (int t = 0; t < 8; ++t) {
            const float* __restrict__ wrow = W1v + (c + t) * HID;
#pragma unroll
            for (int j = 0; j < HID; ++j)
                acc[j] = fmaf(a[t], wrow[j], acc[j]);
        }
    }

    // pack 96 f32 -> 96 bf16 = 12 uint4 (192 B/voxel row)
    uint4* __restrict__ d4 = vc + (size_t)v * 12;
#pragma unroll
    for (int k = 0; k < 12; ++k) {
        const int j = k * 8;
        unsigned a0 = f2bf(acc[j + 0]) | (f2bf(acc[j + 1]) << 16);
        unsigned a1 = f2bf(acc[j + 2]) | (f2bf(acc[j + 3]) << 16);
        unsigned a2 = f2bf(acc[j + 4]) | (f2bf(acc[j + 5]) << 16);
        unsigned a3 = f2bf(acc[j + 6]) | (f2bf(acc[j + 7]) << 16);
        d4[k] = make_uint4(a0, a1, a2, a3);
    }
}

// ---------------------------------------------------------------------------
// Kernel C (UNCHANGED from r4 — control): per-point decoder, bf16 vc rows.
// ---------------------------------------------------------------------------
__global__ __launch_bounds__(256) void point_kernel(
        const int* __restrict__ coords,
        const float* __restrict__ pf,
        const float* __restrict__ po,
        const float* __restrict__ W1,
        const float* __restrict__ W2,
        const float* __restrict__ b2,
        const float* __restrict__ Wc,
        const float* __restrict__ bcomb,
        const uint4* __restrict__ vc,
        float* __restrict__ out) {
    const int i = blockIdx.x * 256 + threadIdx.x;
    if (i >= NPTS) return;

    const int x = coords[i * 3 + 0];
    const int y = coords[i * 3 + 1];
    const int z = coords[i * 3 + 2];
    const int vidx = (z * GRIDW + y) * GRIDW + x;
    const uint4* __restrict__ vrow = vc + (size_t)vidx * 12;

    uint4 vrA[6];
#pragma unroll
    for (int q = 0; q < 6; ++q) vrA[q] = vrow[q];

    const float o0 = po[i * 3 + 0];
    const float o1 = po[i * 3 + 1];
    const float o2 = po[i * 3 + 2];

    float pfr[C_PTC];
    {
        const float4* __restrict__ p4 =
            reinterpret_cast<const float4*>(pf + (size_t)i * C_PTC);
#pragma unroll
        for (int q = 0; q < 8; ++q) {
            float4 v = p4[q];
            pfr[4 * q + 0] = v.x; pfr[4 * q + 1] = v.y;
            pfr[4 * q + 2] = v.z; pfr[4 * q + 3] = v.w;
        }
    }

    float f0 = b2[0], f1 = b2[1], f2 = b2[2];
    uint4 vrB[6];

#pragma unroll
    for (int h = 0; h < 2; ++h) {
        const int j0 = h * HHALF;
        float acc[HHALF];

#pragma unroll
        for (int j = 0; j < HHALF; ++j) {
            float a = fmaf(o2, Wc[2 * HID + j0 + j], bcomb[j0 + j]);
            a = fmaf(o1, Wc[1 * HID + j0 + j], a);
            acc[j] = fmaf(o0, Wc[0 * HID + j0 + j], a);
        }

#pragma unroll
        for (int k = 0; k < C_PTC; ++k) {
            const float fk = pfr[k];
            const float* __restrict__ wrow = W1 + k * HID + j0;
#pragma unroll
            for (int j = 0; j < HHALF; ++j)
                acc[j] = fmaf(fk, wrow[j], acc[j]);
        }

        const uint4* g = (h == 0) ? vrA : vrB;
        if (h == 0) {
#pragma unroll
            for (int q = 0; q < 6; ++q) vrB[q] = vrow[6 + q];
        }
#pragma unroll
        for (int q = 0; q < 6; ++q) {
            const unsigned a0 = g[q].x, a1 = g[q].y, a2 = g[q].z, a3 = g[q].w;
            acc[8 * q + 0] += bflo(a0);
            acc[8 * q + 1] += bfhi(a0);
            acc[8 * q + 2] += bflo(a1);
            acc[8 * q + 3] += bfhi(a1);
            acc[8 * q + 4] += bflo(a2);
            acc[8 * q + 5] += bfhi(a2);
            acc[8 * q + 6] += bflo(a3);
            acc[8 * q + 7] += bfhi(a3);
        }

#pragma unroll
        for (int j = 0; j < HHALF; ++j) {
            const float hh = gelu_fast(acc[j]);
            f0 = fmaf(hh, W2[(j0 + j) * 3 + 0], f0);
            f1 = fmaf(hh, W2[(j0 + j) * 3 + 1], f1);
            f2 = fmaf(hh, W2[(j0 + j) * 3 + 2], f2);
        }
    }

    out[i * 3 + 0] = f0;
    out[i * 3 + 1] = f1;
    out[i * 3 + 2] = f2;
}

// ---------------------------------------------------------------------------
// Fallback (ws too small): direct fp32 gather, unchanged semantics.
// ---------------------------------------------------------------------------
__global__ __launch_bounds__(256) void point_direct_kernel(
        const int* __restrict__ coords,
        const float* __restrict__ vf,
        const float* __restrict__ pf,
        const float* __restrict__ po,
        const float* __restrict__ W1,
        const float* __restrict__ W2,
        const float* __restrict__ b2,
        const float* __restrict__ Wc,
        const float* __restrict__ bcomb,
        float* __restrict__ out) {
    const int i = blockIdx.x * 256 + threadIdx.x;
    if (i >= NPTS) return;

    const int x = coords[i * 3 + 0];
    const int y = coords[i * 3 + 1];
    const int z = coords[i * 3 + 2];
    const int vidx = (z * GRIDW + y) * GRIDW + x;

    float acc[HID];
#pragma unroll
    for (int j = 0; j < HID; ++j) acc[j] = bcomb[j];

    const float* __restrict__ W1v = W1 + C_PTC * HID;
    for (int c = 0; c < C_VOXC; ++c) {
        const float a = vf[(size_t)c * NVOX + vidx];
#pragma unroll
        for (int j = 0; j < HID; ++j)
            acc[j] = fmaf(a, W1v[c * HID + j], acc[j]);
    }

    const float o0 = po[i * 3 + 0];
    const float o1 = po[i * 3 + 1];
    const float o2 = po[i * 3 + 2];
#pragma unroll
    for (int j = 0; j < HID; ++j) {
        float a = fmaf(o2, Wc[2 * HID + j], acc[j]);
        a = fmaf(o1, Wc[1 * HID + j], a);
        acc[j] = fmaf(o0, Wc[0 * HID + j], a);
    }

    const float* __restrict__ pfr = pf + (size_t)i * C_PTC;
    for (int k = 0; k < C_PTC; ++k) {
        const float fk = pfr[k];
#pragma unroll
        for (int j = 0; j < HID; ++j)
            acc[j] = fmaf(fk, W1[k * HID + j], acc[j]);
    }

    float f0 = b2[0], f1 = b2[1], f2 = b2[2];
#pragma unroll
    for (int j = 0; j < HID; ++j) {
        const float hh = gelu_fast(acc[j]);
        f0 = fmaf(hh, W2[j * 3 + 0], f0);
        f1 = fmaf(hh, W2[j * 3 + 1], f1);
        f2 = fmaf(hh, W2[j * 3 + 2], f2);
    }

    out[i * 3 + 0] = f0;
    out[i * 3 + 1] = f1;
    out[i * 3 + 2] = f2;
}

// ---------------------------------------------------------------------------
extern "C" void kernel_launch(void* const* d_in, const int* in_sizes, int n_in,
                              void* d_out, int out_size, void* d_ws, size_t ws_size,
                              hipStream_t stream) {
    const float* vf    = (const float*)d_in[0];
    const int*   vcrd  = (const int*)  d_in[1];
    const float* pf    = (const float*)d_in[2];
    const float* po    = (const float*)d_in[3];
    const float* W_off = (const float*)d_in[4];
    const float* b_off = (const float*)d_in[5];
    const float* W1    = (const float*)d_in[6];
    const float* b1    = (const float*)d_in[7];
    const float* W2    = (const float*)d_in[8];
    const float* b2    = (const float*)d_in[9];
    float* out = (float*)d_out;

    float* Wc    = (float*)d_ws;
    float* bcomb = Wc + 384;
    uint4* vcb   = reinterpret_cast<uint4*>((char*)d_ws + 4096); // 48 MiB bf16

    const size_t need = 4096 + (size_t)NVOX * HID * sizeof(unsigned short);

    fold_kernel<<<1, 128, 0, stream>>>(W_off, b_off, W1, b1, Wc, bcomb);

    if (ws_size >= need) {
        voxgemm_kernel<<<NVOX / 256, 256, 0, stream>>>(vf, W1, vcb);
        point_kernel<<<(NPTS + 255) / 256, 256, 0, stream>>>(
            vcrd, pf, po, W1, W2, b2, Wc, bcomb, vcb, out);
    } else {
        point_direct_kernel<<<(NPTS + 255) / 256, 256, 0, stream>>>(
            vcrd, vf, pf, po, W1, W2, b2, Wc, bcomb, out);
    }
}

// Round 8
// 389.885 us; speedup vs baseline: 1.5683x; 1.5683x over previous
//
#include <hip/hip_runtime.h>
#include <math.h>

#define NPTS   500000
#define GRIDW  64
#define NVOX   (GRIDW*GRIDW*GRIDW)   // 262144
#define C_VOXC 96
#define C_PTC  32
#define OFFD   64
#define HID    96                    // DEC_DIM/2
#define HHALF  48

// bf16 helpers (RNE pack, exact widen) -------------------------------------
__device__ __forceinline__ unsigned f2bf(float f) {
    unsigned u = __float_as_uint(f);
    unsigned r = u + 0x7fffu + ((u >> 16) & 1u);   // round-to-nearest-even
    return r >> 16;
}
__device__ __forceinline__ float bflo(unsigned u) {   // low 16 bits -> f32
    return __uint_as_float(u << 16);
}
__device__ __forceinline__ float bfhi(unsigned u) {   // high 16 bits -> f32
    return __uint_as_float(u & 0xffff0000u);
}

// Branch-free exact-GELU via A&S 7.1.26 erf (abs err 1.5e-7) ---------------
__device__ __forceinline__ float gelu_fast(float s) {
    const float u  = s * 0.70710678118654752440f;
    const float au = fabsf(u);
    const float t  = __fdividef(1.0f, fmaf(0.3275911f, au, 1.0f));
    float p = fmaf(1.061405429f, t, -1.453152027f);
    p = fmaf(p, t, 1.421413741f);
    p = fmaf(p, t, -0.284496736f);
    p = fmaf(p, t, 0.254829592f);
    p *= t;
    const float e = __expf(-u * u);
    float r = fmaf(-p, e, 1.0f);
    r = copysignf(r, u);
    return 0.5f * s * (1.0f + r);
}

// ---------------------------------------------------------------------------
// Kernel A: fold W_off/b_off/b1 through W1's offset rows.
// ---------------------------------------------------------------------------
__global__ void fold_kernel(const float* __restrict__ W_off,
                            const float* __restrict__ b_off,
                            const float* __restrict__ W1,
                            const float* __restrict__ b1,
                            float* __restrict__ Wc,
                            float* __restrict__ bcomb) {
    int j = threadIdx.x;
    if (j >= HID) return;
    float bc = b1[j];
    float w0 = 0.f, w1 = 0.f, w2 = 0.f;
    for (int d = 0; d < OFFD; ++d) {
        float w = W1[(C_PTC + C_VOXC + d) * HID + j];
        bc += b_off[d] * w;
        w0 = fmaf(W_off[0 * OFFD + d], w, w0);
        w1 = fmaf(W_off[1 * OFFD + d], w, w1);
        w2 = fmaf(W_off[2 * OFFD + d], w, w2);
    }
    Wc[0 * HID + j] = w0;
    Wc[1 * HID + j] = w1;
    Wc[2 * HID + j] = w2;
    bcomb[j] = bc;
}

// ---------------------------------------------------------------------------
// Kernel B v4: per-voxel pre-multiply, j SPLIT ACROSS THE 4 WAVES of the
// block. Thread (tv = tid&63, tj = wave id) computes 24 j's for one voxel.
//   acc[24] + ~12 misc => ~40 live VGPRs: fits the allocator's 8-wave/64-VGPR
//   sweet spot with ZERO spill (r4/r6 root cause: acc[96] can never fit the
//   occupancy-driven cap; allocator spills rather than allocate 130 VGPR).
// tj via readfirstlane => provably wave-uniform => W1 addresses scalarize
// (s_load on the scalar pipe), VALU stays pure FMA.
// ---------------------------------------------------------------------------
__global__ __launch_bounds__(256, 8) void voxgemm_kernel(
        const float* __restrict__ vf,
        const float* __restrict__ W1,
        uint4* __restrict__ vc) {
    const int tid = threadIdx.x;
    const int tv  = tid & 63;
    const int tj  = __builtin_amdgcn_readfirstlane(tid >> 6);  // 0..3, uniform
    const int v   = blockIdx.x * 64 + tv;
    const int j0  = tj * 24;
    const float* __restrict__ Wv = W1 + C_PTC * HID + j0;  // row c: Wv[c*HID+jj]

    float acc[24];
#pragma unroll
    for (int jj = 0; jj < 24; ++jj) acc[jj] = 0.f;

#pragma unroll 4
    for (int c = 0; c < C_VOXC; ++c) {
        const float a = vf[(size_t)c * NVOX + v];       // coalesced 256B/wave
        const float* __restrict__ wr = Wv + c * HID;    // wave-uniform
#pragma unroll
        for (int jj = 0; jj < 24; ++jj)
            acc[jj] = fmaf(a, wr[jj], acc[jj]);
    }

    // pack 24 f32 -> 24 bf16 = 3 uint4; this thread owns uint4 slots
    // [tj*3, tj*3+3) of voxel row v (row = 12 uint4 = 192 B).
    uint4* __restrict__ d4 = vc + (size_t)v * 12 + tj * 3;
#pragma unroll
    for (int k = 0; k < 3; ++k) {
        const int j = k * 8;
        unsigned a0 = f2bf(acc[j + 0]) | (f2bf(acc[j + 1]) << 16);
        unsigned a1 = f2bf(acc[j + 2]) | (f2bf(acc[j + 3]) << 16);
        unsigned a2 = f2bf(acc[j + 4]) | (f2bf(acc[j + 5]) << 16);
        unsigned a3 = f2bf(acc[j + 6]) | (f2bf(acc[j + 7]) << 16);
        d4[k] = make_uint4(a0, a1, a2, a3);
    }
}

// ---------------------------------------------------------------------------
// Kernel C v5: per-point decoder, PRESSURE-REDUCED (r3-r4 point spilled:
// VGPR_Count=60 with ~107 live => pfr[32] reloads from scratch inside the
// k-loop were the 2.5x VALU bloat).
//  - no persistent pfr[]: pf float4 loaded just-in-time per k-chunk
//    (pf row re-read once per half: +128B/pt, L2-absorbed)
//  - vrow (6 x uint4) loaded per half, consumed after the FMA block
//  - peak live ~90-115 => launch_bounds(256,4) caps at 128, no spill
// ---------------------------------------------------------------------------
__global__ __launch_bounds__(256, 4) void point_kernel(
        const int* __restrict__ coords,
        const float* __restrict__ pf,
        const float* __restrict__ po,
        const float* __restrict__ W1,
        const float* __restrict__ W2,
        const float* __restrict__ b2,
        const float* __restrict__ Wc,
        const float* __restrict__ bcomb,
        const uint4* __restrict__ vc,
        float* __restrict__ out) {
    const int i = blockIdx.x * 256 + threadIdx.x;
    if (i >= NPTS) return;

    const int x = coords[i * 3 + 0];
    const int y = coords[i * 3 + 1];
    const int z = coords[i * 3 + 2];
    const int vidx = (z * GRIDW + y) * GRIDW + x;
    const uint4* __restrict__ vrow = vc + (size_t)vidx * 12;

    const float o0 = po[i * 3 + 0];
    const float o1 = po[i * 3 + 1];
    const float o2 = po[i * 3 + 2];
    const float4* __restrict__ pf4 =
        reinterpret_cast<const float4*>(pf + (size_t)i * C_PTC);

    float f0 = b2[0], f1 = b2[1], f2 = b2[2];

#pragma unroll
    for (int h = 0; h < 2; ++h) {
        const int j0 = h * HHALF;

        // issue this half's gather early; consumed after ~1700 cyc of FMA
        uint4 vr[6];
#pragma unroll
        for (int q = 0; q < 6; ++q) vr[q] = vrow[h * 6 + q];

        float acc[HHALF];
#pragma unroll
        for (int j = 0; j < HHALF; ++j) {
            float a = fmaf(o2, Wc[2 * HID + j0 + j], bcomb[j0 + j]);
            a = fmaf(o1, Wc[1 * HID + j0 + j], a);
            acc[j] = fmaf(o0, Wc[0 * HID + j0 + j], a);
        }

#pragma unroll 2
        for (int kk = 0; kk < 8; ++kk) {
            const float4 p = pf4[kk];                  // just-in-time pf
            const float pv[4] = {p.x, p.y, p.z, p.w};
#pragma unroll
            for (int t = 0; t < 4; ++t) {
                const float* __restrict__ wr = W1 + (kk * 4 + t) * HID + j0;
#pragma unroll
                for (int j = 0; j < HHALF; ++j)
                    acc[j] = fmaf(pv[t], wr[j], acc[j]);
            }
        }

        // fold in gathered voxel half (bf16 widen = 1 bit-op each)
#pragma unroll
        for (int q = 0; q < 6; ++q) {
            const unsigned a0 = vr[q].x, a1 = vr[q].y,
                           a2 = vr[q].z, a3 = vr[q].w;
            acc[8 * q + 0] += bflo(a0);
            acc[8 * q + 1] += bfhi(a0);
            acc[8 * q + 2] += bflo(a1);
            acc[8 * q + 3] += bfhi(a1);
            acc[8 * q + 4] += bflo(a2);
            acc[8 * q + 5] += bfhi(a2);
            acc[8 * q + 6] += bflo(a3);
            acc[8 * q + 7] += bfhi(a3);
        }

#pragma unroll
        for (int j = 0; j < HHALF; ++j) {
            const float hh = gelu_fast(acc[j]);
            f0 = fmaf(hh, W2[(j0 + j) * 3 + 0], f0);
            f1 = fmaf(hh, W2[(j0 + j) * 3 + 1], f1);
            f2 = fmaf(hh, W2[(j0 + j) * 3 + 2], f2);
        }
    }

    out[i * 3 + 0] = f0;
    out[i * 3 + 1] = f1;
    out[i * 3 + 2] = f2;
}

// ---------------------------------------------------------------------------
// Fallback (ws too small): direct fp32 gather, unchanged semantics.
// ---------------------------------------------------------------------------
__global__ __launch_bounds__(256) void point_direct_kernel(
        const int* __restrict__ coords,
        const float* __restrict__ vf,
        const float* __restrict__ pf,
        const float* __restrict__ po,
        const float* __restrict__ W1,
        const float* __restrict__ W2,
        const float* __restrict__ b2,
        const float* __restrict__ Wc,
        const float* __restrict__ bcomb,
        float* __restrict__ out) {
    const int i = blockIdx.x * 256 + threadIdx.x;
    if (i >= NPTS) return;

    const int x = coords[i * 3 + 0];
    const int y = coords[i * 3 + 1];
    const int z = coords[i * 3 + 2];
    const int vidx = (z * GRIDW + y) * GRIDW + x;

    float acc[HID];
#pragma unroll
    for (int j = 0; j < HID; ++j) acc[j] = bcomb[j];

    const float* __restrict__ W1v = W1 + C_PTC * HID;
    for (int c = 0; c < C_VOXC; ++c) {
        const float a = vf[(size_t)c * NVOX + vidx];
#pragma unroll
        for (int j = 0; j < HID; ++j)
            acc[j] = fmaf(a, W1v[c * HID + j], acc[j]);
    }

    const float o0 = po[i * 3 + 0];
    const float o1 = po[i * 3 + 1];
    const float o2 = po[i * 3 + 2];
#pragma unroll
    for (int j = 0; j < HID; ++j) {
        float a = fmaf(o2, Wc[2 * HID + j], acc[j]);
        a = fmaf(o1, Wc[1 * HID + j], a);
        acc[j] = fmaf(o0, Wc[0 * HID + j], a);
    }

    const float* __restrict__ pfr = pf + (size_t)i * C_PTC;
    for (int k = 0; k < C_PTC; ++k) {
        const float fk = pfr[k];
#pragma unroll
        for (int j = 0; j < HID; ++j)
            acc[j] = fmaf(fk, W1[k * HID + j], acc[j]);
    }

    float f0 = b2[0], f1 = b2[1], f2 = b2[2];
#pragma unroll
    for (int j = 0; j < HID; ++j) {
        const float hh = gelu_fast(acc[j]);
        f0 = fmaf(hh, W2[j * 3 + 0], f0);
        f1 = fmaf(hh, W2[j * 3 + 1], f1);
        f2 = fmaf(hh, W2[j * 3 + 2], f2);
    }

    out[i * 3 + 0] = f0;
    out[i * 3 + 1] = f1;
    out[i * 3 + 2] = f2;
}

// ---------------------------------------------------------------------------
extern "C" void kernel_launch(void* const* d_in, const int* in_sizes, int n_in,
                              void* d_out, int out_size, void* d_ws, size_t ws_size,
                              hipStream_t stream) {
    const float* vf    = (const float*)d_in[0];
    const int*   vcrd  = (const int*)  d_in[1];
    const float* pf    = (const float*)d_in[2];
    const float* po    = (const float*)d_in[3];
    const float* W_off = (const float*)d_in[4];
    const float* b_off = (const float*)d_in[5];
    const float* W1    = (const float*)d_in[6];
    const float* b1    = (const float*)d_in[7];
    const float* W2    = (const float*)d_in[8];
    const float* b2    = (const float*)d_in[9];
    float* out = (float*)d_out;

    float* Wc    = (float*)d_ws;
    float* bcomb = Wc + 384;
    uint4* vcb   = reinterpret_cast<uint4*>((char*)d_ws + 4096); // 48 MiB bf16

    const size_t need = 4096 + (size_t)NVOX * HID * sizeof(unsigned short);

    fold_kernel<<<1, 128, 0, stream>>>(W_off, b_off, W1, b1, Wc, bcomb);

    if (ws_size >= need) {
        voxgemm_kernel<<<NVOX / 64, 256, 0, stream>>>(vf, W1, vcb);
        point_kernel<<<(NPTS + 255) / 256, 256, 0, stream>>>(
            vcrd, pf, po, W1, W2, b2, Wc, bcomb, vcb, out);
    } else {
        point_direct_kernel<<<(NPTS + 255) / 256, 256, 0, stream>>>(
            vcrd, vf, pf, po, W1, W2, b2, Wc, bcomb, out);
    }
}

// Round 9
// 329.064 us; speedup vs baseline: 1.8582x; 1.1848x over previous
//
#include <hip/hip_runtime.h>
#include <math.h>

#define NPTS   500000
#define GRIDW  64
#define NVOX   (GRIDW*GRIDW*GRIDW)   // 262144
#define C_VOXC 96
#define C_PTC  32
#define OFFD   64
#define HID    96                    // DEC_DIM/2

// bf16 helpers (RNE pack, exact widen) -------------------------------------
__device__ __forceinline__ unsigned f2bf(float f) {
    unsigned u = __float_as_uint(f);
    unsigned r = u + 0x7fffu + ((u >> 16) & 1u);   // round-to-nearest-even
    return r >> 16;
}
__device__ __forceinline__ float bflo(unsigned u) {   // low 16 bits -> f32
    return __uint_as_float(u << 16);
}
__device__ __forceinline__ float bfhi(unsigned u) {   // high 16 bits -> f32
    return __uint_as_float(u & 0xffff0000u);
}

// Branch-free exact-GELU via A&S 7.1.26 erf (abs err 1.5e-7) ---------------
__device__ __forceinline__ float gelu_fast(float s) {
    const float u  = s * 0.70710678118654752440f;
    const float au = fabsf(u);
    const float t  = __fdividef(1.0f, fmaf(0.3275911f, au, 1.0f));
    float p = fmaf(1.061405429f, t, -1.453152027f);
    p = fmaf(p, t, 1.421413741f);
    p = fmaf(p, t, -0.284496736f);
    p = fmaf(p, t, 0.254829592f);
    p *= t;
    const float e = __expf(-u * u);
    float r = fmaf(-p, e, 1.0f);
    r = copysignf(r, u);
    return 0.5f * s * (1.0f + r);
}

// ---------------------------------------------------------------------------
// Kernel A: fold W_off/b_off/b1 through W1's offset rows.
// ---------------------------------------------------------------------------
__global__ void fold_kernel(const float* __restrict__ W_off,
                            const float* __restrict__ b_off,
                            const float* __restrict__ W1,
                            const float* __restrict__ b1,
                            float* __restrict__ Wc,
                            float* __restrict__ bcomb) {
    int j = threadIdx.x;
    if (j >= HID) return;
    float bc = b1[j];
    float w0 = 0.f, w1 = 0.f, w2 = 0.f;
    for (int d = 0; d < OFFD; ++d) {
        float w = W1[(C_PTC + C_VOXC + d) * HID + j];
        bc += b_off[d] * w;
        w0 = fmaf(W_off[0 * OFFD + d], w, w0);
        w1 = fmaf(W_off[1 * OFFD + d], w, w1);
        w2 = fmaf(W_off[2 * OFFD + d], w, w2);
    }
    Wc[0 * HID + j] = w0;
    Wc[1 * HID + j] = w1;
    Wc[2 * HID + j] = w2;
    bcomb[j] = bc;
}

// ---------------------------------------------------------------------------
// Kernel B v4 (UNCHANGED — validated in r8: left the top-5, i.e. <155us).
// ---------------------------------------------------------------------------
__global__ __launch_bounds__(256, 8) void voxgemm_kernel(
        const float* __restrict__ vf,
        const float* __restrict__ W1,
        uint4* __restrict__ vc) {
    const int tid = threadIdx.x;
    const int tv  = tid & 63;
    const int tj  = __builtin_amdgcn_readfirstlane(tid >> 6);  // 0..3, uniform
    const int v   = blockIdx.x * 64 + tv;
    const int j0  = tj * 24;
    const float* __restrict__ Wv = W1 + C_PTC * HID + j0;

    float acc[24];
#pragma unroll
    for (int jj = 0; jj < 24; ++jj) acc[jj] = 0.f;

#pragma unroll 4
    for (int c = 0; c < C_VOXC; ++c) {
        const float a = vf[(size_t)c * NVOX + v];
        const float* __restrict__ wr = Wv + c * HID;
#pragma unroll
        for (int jj = 0; jj < 24; ++jj)
            acc[jj] = fmaf(a, wr[jj], acc[jj]);
    }

    uint4* __restrict__ d4 = vc + (size_t)v * 12 + tj * 3;
#pragma unroll
    for (int k = 0; k < 3; ++k) {
        const int j = k * 8;
        unsigned a0 = f2bf(acc[j + 0]) | (f2bf(acc[j + 1]) << 16);
        unsigned a1 = f2bf(acc[j + 2]) | (f2bf(acc[j + 3]) << 16);
        unsigned a2 = f2bf(acc[j + 4]) | (f2bf(acc[j + 5]) << 16);
        unsigned a3 = f2bf(acc[j + 6]) | (f2bf(acc[j + 7]) << 16);
        d4[k] = make_uint4(a0, a1, a2, a3);
    }
}

// ---------------------------------------------------------------------------
// Kernel C v6: WAVE-SPLIT point decoder (voxgemm-v4 pattern).
//   block = 64 points; wave w owns j-range [24w,24w+24); lane l owns point l.
//   - acc[24]/thread => ~50 live VGPRs, no spill, 8 waves/SIMD
//   - W1/Wc/W2/bcomb addresses wave-uniform (j0 via readfirstlane) => s_load
//   - pf tile staged in LDS [64][33] (pad 33 => (l+k)%32 banks, 2-way = free)
//   - vc row: 4 waves x 3 uint4 = the full 192B row, contiguous per point
//   - W2 partials: LDS [4][64][3] + one barrier, wave 0 reduces + stores
// ---------------------------------------------------------------------------
__global__ __launch_bounds__(256, 8) void point_kernel(
        const int* __restrict__ coords,
        const float* __restrict__ pf,
        const float* __restrict__ po,
        const float* __restrict__ W1,
        const float* __restrict__ W2,
        const float* __restrict__ b2,
        const float* __restrict__ Wc,
        const float* __restrict__ bcomb,
        const uint4* __restrict__ vc,
        float* __restrict__ out) {
    __shared__ float pf_s[64][33];
    __shared__ float part[4][64][3];

    const int tid  = threadIdx.x;
    const int lane = tid & 63;
    const int w    = tid >> 6;
    const int wj   = __builtin_amdgcn_readfirstlane(w);   // 0..3 uniform
    const int p0   = blockIdx.x * 64;
    const int p    = p0 + lane;
    const bool valid = (p < NPTS);

    // ---- stage pf tile (each thread: 8 floats of one row) ----
    {
        const int r  = tid >> 2;
        const int c0 = (tid & 3) * 8;
        const int pp = p0 + r;
        float v[8];
        if (pp < NPTS) {
            const float4* __restrict__ src =
                reinterpret_cast<const float4*>(pf + (size_t)pp * C_PTC + c0);
            float4 u0 = src[0], u1 = src[1];
            v[0]=u0.x; v[1]=u0.y; v[2]=u0.z; v[3]=u0.w;
            v[4]=u1.x; v[5]=u1.y; v[6]=u1.z; v[7]=u1.w;
        } else {
#pragma unroll
            for (int t = 0; t < 8; ++t) v[t] = 0.f;
        }
#pragma unroll
        for (int t = 0; t < 8; ++t) pf_s[r][c0 + t] = v[t];
    }

    // ---- per-point loads (issued before the barrier; consumed later) ----
    int vidx = 0;
    float o0 = 0.f, o1 = 0.f, o2 = 0.f;
    uint4 vr0 = make_uint4(0,0,0,0), vr1 = vr0, vr2 = vr0;
    if (valid) {
        const int x = coords[p * 3 + 0];
        const int y = coords[p * 3 + 1];
        const int z = coords[p * 3 + 2];
        vidx = (z * GRIDW + y) * GRIDW + x;
        const uint4* __restrict__ vrow = vc + (size_t)vidx * 12 + wj * 3;
        vr0 = vrow[0]; vr1 = vrow[1]; vr2 = vrow[2];
        o0 = po[p * 3 + 0];
        o1 = po[p * 3 + 1];
        o2 = po[p * 3 + 2];
    }

    __syncthreads();

    const int j0 = wj * 24;

    // init: folded bias + offset projection (all weight reads wave-uniform)
    float acc[24];
#pragma unroll
    for (int jj = 0; jj < 24; ++jj) {
        float a = fmaf(o2, Wc[2 * HID + j0 + jj], bcomb[j0 + jj]);
        a = fmaf(o1, Wc[1 * HID + j0 + jj], a);
        acc[jj] = fmaf(o0, Wc[0 * HID + j0 + jj], a);
    }

    // k-loop: pf from LDS (1 ds_read_b32/k), weights s_load, 24 FMA/k
#pragma unroll
    for (int k = 0; k < C_PTC; ++k) {
        const float s = pf_s[lane][k];
        const float* __restrict__ wr = W1 + k * HID + j0;
#pragma unroll
        for (int jj = 0; jj < 24; ++jj)
            acc[jj] = fmaf(s, wr[jj], acc[jj]);
    }

    // add gathered voxel slice (24 bf16)
    {
        const unsigned a0 = vr0.x, a1 = vr0.y, a2 = vr0.z, a3 = vr0.w;
        acc[0] += bflo(a0);  acc[1] += bfhi(a0);
        acc[2] += bflo(a1);  acc[3] += bfhi(a1);
        acc[4] += bflo(a2);  acc[5] += bfhi(a2);
        acc[6] += bflo(a3);  acc[7] += bfhi(a3);
        const unsigned b0 = vr1.x, b1_ = vr1.y, b2_ = vr1.z, b3 = vr1.w;
        acc[8]  += bflo(b0);  acc[9]  += bfhi(b0);
        acc[10] += bflo(b1_); acc[11] += bfhi(b1_);
        acc[12] += bflo(b2_); acc[13] += bfhi(b2_);
        acc[14] += bflo(b3);  acc[15] += bfhi(b3);
        const unsigned c0 = vr2.x, c1 = vr2.y, c2 = vr2.z, c3 = vr2.w;
        acc[16] += bflo(c0);  acc[17] += bfhi(c0);
        acc[18] += bflo(c1);  acc[19] += bfhi(c1);
        acc[20] += bflo(c2);  acc[21] += bfhi(c2);
        acc[22] += bflo(c3);  acc[23] += bfhi(c3);
    }

    // gelu + partial 24x3 (W2 reads wave-uniform)
    float f0 = 0.f, f1 = 0.f, f2 = 0.f;
#pragma unroll
    for (int jj = 0; jj < 24; ++jj) {
        const float hh = gelu_fast(acc[jj]);
        f0 = fmaf(hh, W2[(j0 + jj) * 3 + 0], f0);
        f1 = fmaf(hh, W2[(j0 + jj) * 3 + 1], f1);
        f2 = fmaf(hh, W2[(j0 + jj) * 3 + 2], f2);
    }
    part[wj][lane][0] = f0;
    part[wj][lane][1] = f1;
    part[wj][lane][2] = f2;

    __syncthreads();

    // wave 0 reduces the 4 wave-partials and stores
    if (w == 0 && valid) {
        const float r0 = part[0][lane][0] + part[1][lane][0] +
                         part[2][lane][0] + part[3][lane][0] + b2[0];
        const float r1 = part[0][lane][1] + part[1][lane][1] +
                         part[2][lane][1] + part[3][lane][1] + b2[1];
        const float r2 = part[0][lane][2] + part[1][lane][2] +
                         part[2][lane][2] + part[3][lane][2] + b2[2];
        out[p * 3 + 0] = r0;
        out[p * 3 + 1] = r1;
        out[p * 3 + 2] = r2;
    }
}

// ---------------------------------------------------------------------------
// Fallback (ws too small): direct fp32 gather, unchanged semantics.
// ---------------------------------------------------------------------------
__global__ __launch_bounds__(256) void point_direct_kernel(
        const int* __restrict__ coords,
        const float* __restrict__ vf,
        const float* __restrict__ pf,
        const float* __restrict__ po,
        const float* __restrict__ W1,
        const float* __restrict__ W2,
        const float* __restrict__ b2,
        const float* __restrict__ Wc,
        const float* __restrict__ bcomb,
        float* __restrict__ out) {
    const int i = blockIdx.x * 256 + threadIdx.x;
    if (i >= NPTS) return;

    const int x = coords[i * 3 + 0];
    const int y = coords[i * 3 + 1];
    const int z = coords[i * 3 + 2];
    const int vidx = (z * GRIDW + y) * GRIDW + x;

    float acc[HID];
#pragma unroll
    for (int j = 0; j < HID; ++j) acc[j] = bcomb[j];

    const float* __restrict__ W1v = W1 + C_PTC * HID;
    for (int c = 0; c < C_VOXC; ++c) {
        const float a = vf[(size_t)c * NVOX + vidx];
#pragma unroll
        for (int j = 0; j < HID; ++j)
            acc[j] = fmaf(a, W1v[c * HID + j], acc[j]);
    }

    const float o0 = po[i * 3 + 0];
    const float o1 = po[i * 3 + 1];
    const float o2 = po[i * 3 + 2];
#pragma unroll
    for (int j = 0; j < HID; ++j) {
        float a = fmaf(o2, Wc[2 * HID + j], acc[j]);
        a = fmaf(o1, Wc[1 * HID + j], a);
        acc[j] = fmaf(o0, Wc[0 * HID + j], a);
    }

    const float* __restrict__ pfr = pf + (size_t)i * C_PTC;
    for (int k = 0; k < C_PTC; ++k) {
        const float fk = pfr[k];
#pragma unroll
        for (int j = 0; j < HID; ++j)
            acc[j] = fmaf(fk, W1[k * HID + j], acc[j]);
    }

    float f0 = b2[0], f1 = b2[1], f2 = b2[2];
#pragma unroll
    for (int j = 0; j < HID; ++j) {
        const float hh = gelu_fast(acc[j]);
        f0 = fmaf(hh, W2[j * 3 + 0], f0);
        f1 = fmaf(hh, W2[j * 3 + 1], f1);
        f2 = fmaf(hh, W2[j * 3 + 2], f2);
    }

    out[i * 3 + 0] = f0;
    out[i * 3 + 1] = f1;
    out[i * 3 + 2] = f2;
}

// ---------------------------------------------------------------------------
extern "C" void kernel_launch(void* const* d_in, const int* in_sizes, int n_in,
                              void* d_out, int out_size, void* d_ws, size_t ws_size,
                              hipStream_t stream) {
    const float* vf    = (const float*)d_in[0];
    const int*   vcrd  = (const int*)  d_in[1];
    const float* pf    = (const float*)d_in[2];
    const float* po    = (const float*)d_in[3];
    const float* W_off = (const float*)d_in[4];
    const float* b_off = (const float*)d_in[5];
    const float* W1    = (const float*)d_in[6];
    const float* b1    = (const float*)d_in[7];
    const float* W2    = (const float*)d_in[8];
    const float* b2    = (const float*)d_in[9];
    float* out = (float*)d_out;

    float* Wc    = (float*)d_ws;
    float* bcomb = Wc + 384;
    uint4* vcb   = reinterpret_cast<uint4*>((char*)d_ws + 4096); // 48 MiB bf16

    const size_t need = 4096 + (size_t)NVOX * HID * sizeof(unsigned short);

    fold_kernel<<<1, 128, 0, stream>>>(W_off, b_off, W1, b1, Wc, bcomb);

    if (ws_size >= need) {
        voxgemm_kernel<<<NVOX / 64, 256, 0, stream>>>(vf, W1, vcb);
        point_kernel<<<(NPTS + 63) / 64, 256, 0, stream>>>(
            vcrd, pf, po, W1, W2, b2, Wc, bcomb, vcb, out);
    } else {
        point_direct_kernel<<<(NPTS + 255) / 256, 256, 0, stream>>>(
            vcrd, vf, pf, po, W1, W2, b2, Wc, bcomb, out);
    }
}